// Round 8
// baseline (103.788 us; speedup 1.0000x reference)
//
#include <hip/hip_runtime.h>
#include <hip/hip_bf16.h>
#include <math.h>

#define B_ 4
#define S_ 2048
#define H_ 1024
#define KC 128
#define EPSF 1e-8f

typedef __attribute__((ext_vector_type(8))) short bf16x8;
typedef __attribute__((ext_vector_type(4))) float f32x4;

static __device__ inline unsigned short f2b(float f) {
    unsigned u = __float_as_uint(f);
    return (unsigned short)((u + 0x7fffu + ((u >> 16) & 1u)) >> 16);  // RNE
}

static __device__ inline unsigned long long shflx64(unsigned long long v, int m) {
    int lo = __shfl_xor((int)(unsigned)(v & 0xffffffffull), m, 64);
    int hi = __shfl_xor((int)(unsigned)(v >> 32), m, 64);
    return ((unsigned long long)(unsigned)hi << 32) | (unsigned)lo;
}

#define CROSS_STAGE(k, j) do {                                              \
    const int lm = (j) >> 3;                                                \
    const bool upL  = (((lane) * 8) & (k)) == 0;                            \
    const bool lowr = ((lane) & lm) == 0;                                   \
    _Pragma("unroll")                                                       \
    for (int r = 0; r < 8; ++r) {                                           \
        unsigned long long o = shflx64(e[r], lm);                           \
        e[r] = ((upL == lowr) == (e[r] < o)) ? e[r] : o;                    \
    }                                                                       \
} while (0)

#define INTRA_STAGE(j, k) do {                                              \
    _Pragma("unroll")                                                       \
    for (int r = 0; r < 8; ++r) if (!(r & (j))) {                           \
        bool up = ((((lane) * 8 + r) & (k)) == 0);                          \
        unsigned long long a = e[r], b = e[r | (j)];                        \
        if (up ? (a > b) : (a < b)) { e[r] = b; e[r | (j)] = a; }           \
    }                                                                       \
} while (0)

static __device__ inline void wave_sort512(unsigned long long e[8], int lane) {
    INTRA_STAGE(1, 2);
    INTRA_STAGE(2, 4);  INTRA_STAGE(1, 4);
    INTRA_STAGE(4, 8);  INTRA_STAGE(2, 8);  INTRA_STAGE(1, 8);
    CROSS_STAGE(16, 8);
    INTRA_STAGE(4, 16); INTRA_STAGE(2, 16); INTRA_STAGE(1, 16);
    CROSS_STAGE(32, 16); CROSS_STAGE(32, 8);
    INTRA_STAGE(4, 32); INTRA_STAGE(2, 32); INTRA_STAGE(1, 32);
    CROSS_STAGE(64, 32); CROSS_STAGE(64, 16); CROSS_STAGE(64, 8);
    INTRA_STAGE(4, 64); INTRA_STAGE(2, 64); INTRA_STAGE(1, 64);
    CROSS_STAGE(128, 64); CROSS_STAGE(128, 32); CROSS_STAGE(128, 16);
    CROSS_STAGE(128, 8);
    INTRA_STAGE(4, 128); INTRA_STAGE(2, 128); INTRA_STAGE(1, 128);
    CROSS_STAGE(256, 128); CROSS_STAGE(256, 64); CROSS_STAGE(256, 32);
    CROSS_STAGE(256, 16); CROSS_STAGE(256, 8);
    INTRA_STAGE(4, 256); INTRA_STAGE(2, 256); INTRA_STAGE(1, 256);
    CROSS_STAGE(512, 256); CROSS_STAGE(512, 128); CROSS_STAGE(512, 64);
    CROSS_STAGE(512, 32); CROSS_STAGE(512, 16); CROSS_STAGE(512, 8);
    INTRA_STAGE(4, 512); INTRA_STAGE(2, 512); INTRA_STAGE(1, 512);
}

// ------------------------------------------------------------------
// Kernel 1 (prep): blocks 0..3071 transpose+convert weights to bf16;
// blocks 3072..3079 do top-K selection (register bitonic, 1 barrier).
// ------------------------------------------------------------------
__global__ __launch_bounds__(256) void prep_kernel(
    const float* __restrict__ Wk, const float* __restrict__ Wv,
    const float* __restrict__ Wbil,
    unsigned short* __restrict__ Wt,    // [3][1024][1024] bf16 (N-major)
    const float* __restrict__ logits,   // [B,S,3]
    const int*   __restrict__ mask,     // [B,S]
    int* __restrict__ key_idx,          // [B,K]
    int* __restrict__ val_idx,          // [B,K]
    float* __restrict__ out_idx)        // d_out + B*K*V
{
    __shared__ float tile[32][33];
    __shared__ unsigned long long cand[512];
    const int tid = threadIdx.x;

    if (blockIdx.x < 3072) {
        const int z = blockIdx.x >> 10;
        const int remb = blockIdx.x & 1023;
        const float* Win = (z == 0) ? Wk : (z == 1) ? Wv : Wbil;
        unsigned short* out = Wt + (size_t)z * H_ * H_;
        const int n0 = (remb & 31) * 32, k0 = (remb >> 5) * 32;
        const int r = tid >> 3, c0 = (tid & 7) * 4;

        float4 v = *(const float4*)(Win + (size_t)(k0 + r) * H_ + n0 + c0);
        tile[r][c0 + 0] = v.x; tile[r][c0 + 1] = v.y;
        tile[r][c0 + 2] = v.z; tile[r][c0 + 3] = v.w;
        __syncthreads();

        short4 o;
        o.x = (short)f2b(tile[c0 + 0][r]);
        o.y = (short)f2b(tile[c0 + 1][r]);
        o.z = (short)f2b(tile[c0 + 2][r]);
        o.w = (short)f2b(tile[c0 + 3][r]);
        *(short4*)(out + (size_t)(n0 + r) * H_ + k0 + c0) = o;
        return;
    }

    const int blk = blockIdx.x - 3072;   // 0..7
    const int b   = blk >> 1;
    const int cls = (blk & 1) ? 2 : 1;
    const int w    = tid >> 6;
    const int lane = tid & 63;

    unsigned long long e[8];
    #pragma unroll
    for (int r = 0; r < 8; ++r) {
        int s = w * 512 + lane * 8 + r;
        float l0 = logits[(b * S_ + s) * 3 + 0];
        float l1 = logits[(b * S_ + s) * 3 + 1];
        float l2 = logits[(b * S_ + s) * 3 + 2];
        int pred = 0; float bl = l0;
        if (l1 > bl) { bl = l1; pred = 1; }
        if (l2 > bl) { bl = l2; pred = 2; }
        float c = -1.0f;
        if (pred == cls && mask[b * S_ + s] == 1) {
            double m = (double)bl;
            double e0 = exp((double)l0 - m);
            double e1 = exp((double)l1 - m);
            double e2 = exp((double)l2 - m);
            c = (float)(((cls == 1) ? e1 : e2) / (e0 + e1 + e2));
        }
        unsigned int u = __float_as_uint(c);
        unsigned int mono = (u & 0x80000000u) ? ~u : (u | 0x80000000u);
        e[r] = ((unsigned long long)(~mono) << 32) | (unsigned int)s;
    }

    wave_sort512(e, lane);

    if (lane < 16) {
        #pragma unroll
        for (int r = 0; r < 8; ++r) cand[w * 128 + lane * 8 + r] = e[r];
    }
    __syncthreads();

    if (w == 0) {
        #pragma unroll
        for (int r = 0; r < 8; ++r) e[r] = cand[lane * 8 + r];
        wave_sort512(e, lane);
        if (lane < 16) {
            int* idx_out = (blk & 1) ? (val_idx + b * KC) : (key_idx + b * KC);
            float* oidx  = out_idx + ((blk & 1) ? B_ * KC : 0) + b * KC;
            #pragma unroll
            for (int r = 0; r < 8; ++r) {
                int sel = (int)(e[r] & 0xffffffffu);
                idx_out[lane * 8 + r] = sel;
                oidx[lane * 8 + r] = (float)sel;
            }
        }
    }
}

// ------------------------------------------------------------------
// Kernel 2: gather seq rows by idx, convert to bf16.
// ------------------------------------------------------------------
__global__ __launch_bounds__(256) void gatherconv_kernel(
    const float* __restrict__ seq,     // [B,S,H]
    const int* __restrict__ key_idx, const int* __restrict__ val_idx,
    unsigned short* __restrict__ Abf)  // [1024][1024]
{
    const int row = blockIdx.x;
    const int tid = threadIdx.x;
    int b, srow;
    if (row < 512) { b = row >> 7; srow = key_idx[row]; }
    else           { b = (row - 512) >> 7; srow = val_idx[row - 512]; }
    const float* src = seq + ((size_t)b * S_ + srow) * H_ + tid * 4;
    float4 v = *(const float4*)src;
    short4 o;
    o.x = (short)f2b(v.x); o.y = (short)f2b(v.y);
    o.z = (short)f2b(v.z); o.w = (short)f2b(v.w);
    *(short4*)(Abf + (size_t)row * H_ + tid * 4) = o;
}

// ------------------------------------------------------------------
// Kernel 3: MFMA GEMM  C[m][n] = A[m][:] . Wt[n][:]  (+bias), bf16->bf16.
// 32x32 tile per wave (acc 2x2), grid (32,16,z): 4 waves/CU at z=2.
// ------------------------------------------------------------------
__global__ __launch_bounds__(64) void gemm_mfma_kernel(
    const unsigned short* __restrict__ A,   // [z*512+512][1024] bf16
    const unsigned short* __restrict__ Wt,  // [z][1024][1024] bf16 (N-major)
    const float* __restrict__ b0, const float* __restrict__ b1,
    unsigned short* __restrict__ Cout)      // [z*512+512][1024] bf16
{
    const int z = blockIdx.z;
    A    += (size_t)z * 512 * H_;
    Wt   += (size_t)z * H_ * H_;
    Cout += (size_t)z * 512 * H_;
    const float* bias = z ? b1 : b0;

    const int l  = threadIdx.x;
    const int m0 = blockIdx.y * 32;
    const int n0 = blockIdx.x * 32;
    const int r  = l & 15;
    const int kb = (l >> 4) * 8;

    f32x4 acc[2][2] = {};
    const unsigned short* a0 = A + (size_t)(m0 + r) * H_ + kb;
    const unsigned short* a1 = a0 + 16 * H_;
    const unsigned short* w0 = Wt + (size_t)(n0 + r) * H_ + kb;
    const unsigned short* w1 = w0 + 16 * H_;

    #pragma unroll 4
    for (int k0 = 0; k0 < H_; k0 += 32) {
        bf16x8 av[2], bv[2];
        av[0] = *(const bf16x8*)(a0 + k0);
        av[1] = *(const bf16x8*)(a1 + k0);
        bv[0] = *(const bf16x8*)(w0 + k0);
        bv[1] = *(const bf16x8*)(w1 + k0);
        #pragma unroll
        for (int i = 0; i < 2; ++i)
            #pragma unroll
            for (int j = 0; j < 2; ++j)
                acc[i][j] = __builtin_amdgcn_mfma_f32_16x16x32_bf16(
                    av[i], bv[j], acc[i][j], 0, 0, 0);
    }

    const int orow = (l >> 4) * 4, ocol = l & 15;
    #pragma unroll
    for (int i = 0; i < 2; ++i) {
        #pragma unroll
        for (int j = 0; j < 2; ++j) {
            int n = n0 + j * 16 + ocol;
            float bv_ = bias ? bias[n] : 0.0f;
            #pragma unroll
            for (int g = 0; g < 4; ++g) {
                int m = m0 + i * 16 + orow + g;
                Cout[(size_t)m * H_ + n] = f2b(acc[i][j][g] + bv_);
            }
        }
    }
}

// ------------------------------------------------------------------
// Kernel 4: biaffine via MFMA: scores[b,k,v] = kbt[bk,:].vrep[bv,:] + bbil
// ------------------------------------------------------------------
__global__ __launch_bounds__(64) void biaffine_mfma_kernel(
    const unsigned short* __restrict__ kbt,   // [512][1024] bf16 (b-major)
    const unsigned short* __restrict__ vrep,  // [512][1024] bf16
    const float* __restrict__ bbil,
    float* __restrict__ scores)               // [B,K,V] = d_out
{
    const int b  = blockIdx.z;
    const int l  = threadIdx.x;
    const int m0 = blockIdx.y * 32;
    const int n0 = blockIdx.x * 32;
    const int r  = l & 15;
    const int kb = (l >> 4) * 8;

    f32x4 acc[2][2] = {};
    const unsigned short* a0 = kbt  + (size_t)(b * KC + m0 + r) * H_ + kb;
    const unsigned short* a1 = a0 + 16 * H_;
    const unsigned short* w0 = vrep + (size_t)(b * KC + n0 + r) * H_ + kb;
    const unsigned short* w1 = w0 + 16 * H_;

    #pragma unroll 4
    for (int k0 = 0; k0 < H_; k0 += 32) {
        bf16x8 av[2], bv[2];
        av[0] = *(const bf16x8*)(a0 + k0);
        av[1] = *(const bf16x8*)(a1 + k0);
        bv[0] = *(const bf16x8*)(w0 + k0);
        bv[1] = *(const bf16x8*)(w1 + k0);
        #pragma unroll
        for (int i = 0; i < 2; ++i)
            #pragma unroll
            for (int j = 0; j < 2; ++j)
                acc[i][j] = __builtin_amdgcn_mfma_f32_16x16x32_bf16(
                    av[i], bv[j], acc[i][j], 0, 0, 0);
    }

    float bb = *bbil;
    const int orow = (l >> 4) * 4, ocol = l & 15;
    #pragma unroll
    for (int i = 0; i < 2; ++i)
        #pragma unroll
        for (int j = 0; j < 2; ++j)
            #pragma unroll
            for (int g = 0; g < 4; ++g) {
                int m = m0 + i * 16 + orow + g;
                int n = n0 + j * 16 + ocol;
                scores[((size_t)b * KC + m) * KC + n] = acc[i][j][g] + bb;
            }
}

// ------------------------------------------------------------------
// Kernel 5: spatial features + MLP(8->64->32) + final MLP(33->16->1).
// float4 LDS layout: ds_read_b128 instead of b32. In-place on d_out.
// ------------------------------------------------------------------
__global__ __launch_bounds__(128) void fused_spatial_kernel(
    const float* __restrict__ bboxes,  // [B,S,4]
    const int* __restrict__ key_idx, const int* __restrict__ val_idx,
    const float* __restrict__ Ws1, const float* __restrict__ bs1,
    const float* __restrict__ Ws2, const float* __restrict__ bs2,
    const float* __restrict__ Wf1, const float* __restrict__ bf1,
    const float* __restrict__ Wf2, const float* __restrict__ bf2,
    float* sc)                          // [B,K,V] (biaffine in, score out)
{
    __shared__ float4 sWs1T[64 * 2];   // [j][i4]: sWs1T[j*2+q][x] = Ws1[(4q+x)*64+j]
    __shared__ float  sbs1[64];
    __shared__ float4 sWs2v[64 * 8];   // [j][t4] = Ws2[j][4t..4t+3]
    __shared__ float4 sbs2v[8];
    __shared__ float  sWf1c0[16];      // Wf1[0][t]
    __shared__ float4 sWf1v[16 * 8];   // [t][q][x] = Wf1[1+4q+x][t]
    __shared__ float  sbf1[16];
    __shared__ float  sWf2[16];

    const int tid = threadIdx.x;
    for (int i = tid; i < 128; i += 128) {
        int j = i >> 1, q = i & 1;
        sWs1T[i] = (float4){Ws1[(4*q+0)*64+j], Ws1[(4*q+1)*64+j],
                            Ws1[(4*q+2)*64+j], Ws1[(4*q+3)*64+j]};
    }
    for (int i = tid; i < 64;  i += 128) sbs1[i] = bs1[i];
    for (int i = tid; i < 512; i += 128) sWs2v[i] = ((const float4*)Ws2)[i];
    if (tid < 8)  sbs2v[tid] = ((const float4*)bs2)[tid];
    if (tid < 16) sWf1c0[tid] = Wf1[tid];
    for (int i = tid; i < 128; i += 128) {
        int t = i >> 3, q = i & 7;
        sWf1v[i] = (float4){Wf1[(1+4*q+0)*16+t], Wf1[(1+4*q+1)*16+t],
                            Wf1[(1+4*q+2)*16+t], Wf1[(1+4*q+3)*16+t]};
    }
    if (tid < 16) sbf1[tid] = bf1[tid];
    if (tid < 16) sWf2[tid] = Wf2[tid];
    __syncthreads();

    const int gid = blockIdx.x * 128 + tid;   // block = one (b,k) row, tid = v
    const int b = gid >> 14;
    const int rem = gid & 16383;
    const int k = rem >> 7;
    const int v = rem & 127;

    const float* kbx = bboxes + ((size_t)b * S_ + key_idx[b * KC + k]) * 4;
    const float* vbx = bboxes + ((size_t)b * S_ + val_idx[b * KC + v]) * 4;
    float k0 = kbx[0], k1 = kbx[1], k2 = kbx[2], k3 = kbx[3];
    float v0 = vbx[0], v1 = vbx[1], v2 = vbx[2], v3 = vbx[3];

    float kcx = (k0 + k2) * 0.5f, kcy = (k1 + k3) * 0.5f;
    float vcx = (v0 + v2) * 0.5f, vcy = (v1 + v3) * 0.5f;
    float dx = vcx - kcx, dy = vcy - kcy;
    float dist = sqrtf(dx * dx + dy * dy + EPSF);
    float angle = atan2f(dy, dx);
    float kh = k3 - k1, vh = v3 - v1, kw = k2 - k0, vw = v2 - v0;
    float h_ov = fmaxf(fminf(k3, v3) - fmaxf(k1, v1), 0.0f);
    float h_align = h_ov / (fminf(kh, vh) + EPSF);
    float v_ov = fmaxf(fminf(k2, v2) - fmaxf(k0, v0), 0.0f);
    float v_align = v_ov / (fminf(kw, vw) + EPSF);
    float area_ratio = (vh * vw) / (kh * kw + EPSF);
    float aspect = (vw / (vh + EPSF)) / (kw / (kh + EPSF));

    float4 sfa = {dx, dy, dist, angle};
    float4 sfb = {h_align, v_align, area_ratio, aspect};

    float4 h2v[8];
    #pragma unroll
    for (int q = 0; q < 8; ++q) h2v[q] = sbs2v[q];

    for (int j = 0; j < 64; ++j) {
        float4 w1a = sWs1T[j * 2], w1b = sWs1T[j * 2 + 1];
        float a = sbs1[j]
                + sfa.x * w1a.x + sfa.y * w1a.y + sfa.z * w1a.z + sfa.w * w1a.w
                + sfb.x * w1b.x + sfb.y * w1b.y + sfb.z * w1b.z + sfb.w * w1b.w;
        a = fmaxf(a, 0.0f);
        const float4* w2 = &sWs2v[j * 8];
        #pragma unroll
        for (int q = 0; q < 8; ++q) {
            float4 w = w2[q];
            h2v[q].x += a * w.x; h2v[q].y += a * w.y;
            h2v[q].z += a * w.z; h2v[q].w += a * w.w;
        }
    }

    float c0 = sc[gid];
    float score = bf2[0];
    for (int t = 0; t < 16; ++t) {
        float f = sbf1[t] + c0 * sWf1c0[t];
        const float4* w = &sWf1v[t * 8];
        #pragma unroll
        for (int q = 0; q < 8; ++q) {
            float4 ww = w[q];
            f += h2v[q].x * ww.x + h2v[q].y * ww.y
               + h2v[q].z * ww.z + h2v[q].w * ww.w;
        }
        score += fmaxf(f, 0.0f) * sWf2[t];
    }
    sc[gid] = score;
}

// ------------------------------------------------------------------
extern "C" void kernel_launch(void* const* d_in, const int* in_sizes, int n_in,
                              void* d_out, int out_size, void* d_ws, size_t ws_size,
                              hipStream_t stream) {
    const float* seq    = (const float*)d_in[0];
    const float* logits = (const float*)d_in[1];
    const float* bboxes = (const float*)d_in[2];
    const int*   mask   = (const int*)d_in[3];
    const float* Wk   = (const float*)d_in[4];
    const float* bk   = (const float*)d_in[5];
    const float* Wv   = (const float*)d_in[6];
    const float* bv   = (const float*)d_in[7];
    const float* Wbil = (const float*)d_in[8];
    const float* bbil = (const float*)d_in[9];
    const float* Ws1  = (const float*)d_in[10];
    const float* bs1  = (const float*)d_in[11];
    const float* Ws2  = (const float*)d_in[12];
    const float* bs2  = (const float*)d_in[13];
    const float* Wf1  = (const float*)d_in[14];
    const float* bf1  = (const float*)d_in[15];
    const float* Wf2  = (const float*)d_in[16];
    const float* bf2  = (const float*)d_in[17];

    float* out = (float*)d_out;        // scores [65536] | key_idx | val_idx
    char* ws = (char*)d_ws;

    int* key_idx = (int*)ws;
    int* val_idx = key_idx + B_ * KC;
    unsigned short* Wt   = (unsigned short*)(ws + 4096);
    unsigned short* Abf  = Wt + (size_t)3 * H_ * H_;
    unsigned short* kbt  = Abf;                       // alias (Abf dead by then)
    unsigned short* reps = Abf + (size_t)H_ * H_;
    unsigned short* krep = reps;
    unsigned short* vrep = reps + (size_t)512 * H_;

    prep_kernel<<<3080, 256, 0, stream>>>(Wk, Wv, Wbil, Wt,
                                          logits, mask, key_idx, val_idx,
                                          out + B_ * KC * KC);
    gatherconv_kernel<<<1024, 256, 0, stream>>>(seq, key_idx, val_idx, Abf);

    gemm_mfma_kernel<<<dim3(32, 16, 2), 64, 0, stream>>>(
        Abf, Wt, bk, bv, reps);
    gemm_mfma_kernel<<<dim3(32, 16, 1), 64, 0, stream>>>(
        krep, Wt + (size_t)2 * H_ * H_, nullptr, nullptr, kbt);

    biaffine_mfma_kernel<<<dim3(4, 4, B_), 64, 0, stream>>>(
        kbt, vrep, bbil, out);

    fused_spatial_kernel<<<(B_ * KC * KC) / 128, 128, 0, stream>>>(
        bboxes, key_idx, val_idx,
        Ws1, bs1, Ws2, bs2, Wf1, bf1, Wf2, bf2, out);
}